// Round 1
// baseline (56.620 us; speedup 1.0000x reference)
//
#include <hip/hip_runtime.h>
#include <hip/hip_bf16.h>

// TaylorExp: out[b,h,s, i*16+j] = x[b,h,s,i] * x[b,h,s,j] / sqrt(16)
// Shapes: x [4,16,4096,16] fp32 -> out [4,16,4096,256] fp32.
// Memory-bound: 16 MiB read + 256 MiB write. One wave per row; lane l writes
// a float4 at out[row*256 + 4l], needing x[l>>2] (scalar) and x[(l&3)*4 .. +3]
// (float4). Coalesced 1 KiB store per wave.

__global__ __launch_bounds__(256) void TaylorExp_23983097380979_kernel(
    const float* __restrict__ x, float* __restrict__ out, long nrows) {
    const int lane = threadIdx.x & 63;
    const int wave_in_block = threadIdx.x >> 6;      // 0..3
    const long waves_per_grid = (long)gridDim.x * 4;
    long row = (long)blockIdx.x * 4 + wave_in_block;

    const int i  = lane >> 2;        // 0..15  (outer index)
    const int j0 = (lane & 3) * 4;   // 0,4,8,12 (inner index block)

    for (; row < nrows; row += waves_per_grid) {
        const float* xr = x + row * 16;
        const float  xi = xr[i];
        const float4 xj = *reinterpret_cast<const float4*>(xr + j0);
        const float  s  = xi * 0.25f;                // 1/sqrt(16)
        float4 o;
        o.x = s * xj.x;
        o.y = s * xj.y;
        o.z = s * xj.z;
        o.w = s * xj.w;
        *reinterpret_cast<float4*>(out + row * 256 + lane * 4) = o;
    }
}

extern "C" void kernel_launch(void* const* d_in, const int* in_sizes, int n_in,
                              void* d_out, int out_size, void* d_ws, size_t ws_size,
                              hipStream_t stream) {
    const float* x = (const float*)d_in[0];
    float* out = (float*)d_out;

    const long nrows = (long)in_sizes[0] / 16;       // B*H*S = 262144
    const long blocks_needed = (nrows + 3) / 4;      // 4 waves (rows) per block
    const int grid = (int)(blocks_needed < 2048 ? blocks_needed : 2048);

    TaylorExp_23983097380979_kernel<<<grid, 256, 0, stream>>>(x, out, nrows);
}

// Round 3
// 52.123 us; speedup vs baseline: 1.0863x; 1.0863x over previous
//
#include <hip/hip_runtime.h>
#include <hip/hip_bf16.h>

// TaylorExp: out[b,h,s, i*16+j] = x[b,h,s,i] * x[b,h,s,j] / sqrt(16)
// x [4,16,4096,16] fp32 -> out [4,16,4096,256] fp32.
// Memory-bound: 16.8 MB read + 268 MB write. One wave per row; lane l writes
// 16 B at out[row*256+4l] (coalesced 1 KiB/wave).
// R3: same as R2 but using clang ext_vector_type for the vector ops —
// __builtin_nontemporal_store rejects HIP's float4 class type.
// Software-pipelined x load (prefetch next row before storing current) +
// nontemporal stores (268 MB output streams past the 32 MB L2).

typedef float f32x4 __attribute__((ext_vector_type(4)));

__global__ __launch_bounds__(256) void TaylorExp_23983097380979_kernel(
    const float* __restrict__ x, float* __restrict__ out, long nrows) {
    const int lane = threadIdx.x & 63;
    const int wave_in_block = threadIdx.x >> 6;      // 0..3
    const long stride = (long)gridDim.x * 4;
    long row = (long)blockIdx.x * 4 + wave_in_block;

    const int i  = lane >> 2;        // 0..15   outer index
    const int j0 = (lane & 3) * 4;   // 0,4,8,12 inner index block

    if (row >= nrows) return;

    // prologue: load first row
    const float* xr = x + row * 16;
    float  xi = xr[i];
    f32x4  xj = *reinterpret_cast<const f32x4*>(xr + j0);

    for (;;) {
        const long next = row + stride;
        const bool has_next = next < nrows;
        float xi_n = 0.0f;
        f32x4 xj_n = (f32x4)0.0f;
        if (has_next) {
            const float* xn = x + next * 16;
            xi_n = xn[i];                                    // issue early;
            xj_n = *reinterpret_cast<const f32x4*>(xn + j0); // overlaps store
        }

        const float s = xi * 0.25f;                  // 1/sqrt(16)
        f32x4 o = xj * s;
        __builtin_nontemporal_store(
            o, reinterpret_cast<f32x4*>(out + row * 256 + lane * 4));

        if (!has_next) break;
        row = next;
        xi = xi_n;
        xj = xj_n;
    }
}

extern "C" void kernel_launch(void* const* d_in, const int* in_sizes, int n_in,
                              void* d_out, int out_size, void* d_ws, size_t ws_size,
                              hipStream_t stream) {
    const float* x = (const float*)d_in[0];
    float* out = (float*)d_out;

    const long nrows = (long)in_sizes[0] / 16;       // B*H*S = 262144
    const long blocks_needed = (nrows + 3) / 4;      // 4 waves (rows) per block
    const int grid = (int)(blocks_needed < 2048 ? blocks_needed : 2048);

    TaylorExp_23983097380979_kernel<<<grid, 256, 0, stream>>>(x, out, nrows);
}

// Round 4
// 44.698 us; speedup vs baseline: 1.2667x; 1.1661x over previous
//
#include <hip/hip_runtime.h>
#include <hip/hip_bf16.h>

// TaylorExp: out[b,h,s, i*16+j] = x[b,h,s,i] * x[b,h,s,j] / sqrt(16)
// x [4,16,4096,16] fp32 -> out [4,16,4096,256] fp32.
// Memory-bound: 16.8 MB read + 268 MB write; floor ~42 us at the 6.8 TB/s
// demonstrated write ceiling (rocclr fillBuffer on the same chip).
// R4: mimic the fill kernel's regime exactly — full grid, NO loop: each
// thread does {1 scalar load, 1 float4 load, 4 mul, 1 nontemporal 16B store}.
// 65536 blocks x 256 thr; each wave emits one coalesced 1 KiB store.
// Previous grid-stride pipelined loop (52.1 us) paid per-iter loop control +
// predicated prefetch; the fill kernel proves max-TLP no-loop hits 7 TB/s.

typedef float f32x4 __attribute__((ext_vector_type(4)));

__global__ __launch_bounds__(256) void TaylorExp_23983097380979_kernel(
    const float* __restrict__ x, float* __restrict__ out, long nvec4) {
    const long t = (long)blockIdx.x * 256 + threadIdx.x;  // one float4 per thread
    if (t >= nvec4) return;

    const long row  = t >> 6;            // one wave == one row of 256 outputs
    const int  lane = (int)(t & 63);
    const int  i  = lane >> 2;           // 0..15   outer index
    const int  j0 = (lane & 3) * 4;      // 0,4,8,12 inner index block

    const float* xr = x + row * 16;
    const float  xi = xr[i];
    const f32x4  xj = *reinterpret_cast<const f32x4*>(xr + j0);

    const f32x4 o = xj * (xi * 0.25f);   // 1/sqrt(16)
    __builtin_nontemporal_store(o, reinterpret_cast<f32x4*>(out) + t);
}

extern "C" void kernel_launch(void* const* d_in, const int* in_sizes, int n_in,
                              void* d_out, int out_size, void* d_ws, size_t ws_size,
                              hipStream_t stream) {
    const float* x = (const float*)d_in[0];
    float* out = (float*)d_out;

    const long nvec4 = (long)out_size / 4;           // 16,777,216 float4 stores
    const long grid  = (nvec4 + 255) / 256;          // 65,536 blocks

    TaylorExp_23983097380979_kernel<<<(int)grid, 256, 0, stream>>>(x, out, nvec4);
}